// Round 5
// baseline (2602.338 us; speedup 1.0000x reference)
//
#include <hip/hip_runtime.h>

#define T_SEQ 1024
#define NBATCH 256
#define DIN 128
#define HID 64
#define DOUT 128

typedef float v2f __attribute__((ext_vector_type(2)));

// ---------------- LDS layouts ----------------
// Encoder (per ping-pong buffer of 352 floats):
//  op0 [0..204):  [x:128 | h0:64]; 4 k-slices of 48 floats at 0,52,104,156
//                 x[k] -> k + 4*(k/48); h0[j] -> 136+j (j<16) else 140+j
//  op1 [208..348): [h0:64 | h1:64]; 32-float slices padded to 36:
//                 h0[j] -> 208 + j + 4*(j>>5); h1[j] -> 280 + j + 4*(j>>5)
// Decoder (overlaid):
//  op0 [0..140):   [h1:64 | h0:64], pos(i)=i+4*(i>>5); slices 0,36,72,108
//  op1 [144..284): [h0:64 | h1:64], pos=144+i+4*(i>>5); slices 144,180,216,252
#define BUFSZ 352

__device__ __forceinline__ float rcp_f(float x) { return __builtin_amdgcn_rcpf(x); }

// tanh(x) = 1 - 2/(1+e^{2x}); inf-safe
__device__ __forceinline__ float tanh_f(float x) {
  float m = __expf(2.0f * x);
  return fmaf(-2.0f, rcp_f(1.0f + m), 1.0f);
}

// ds_swizzle BitMode: src = ((lane & and) | or) ^ xor; offset=(xor<<10)|(or<<5)|and
template<int IMM>
__device__ __forceinline__ float swz(float v) {
  return __uint_as_float((unsigned)__builtin_amdgcn_ds_swizzle((int)__float_as_uint(v), IMM));
}

// quad-perm DPP butterfly add on the VALU pipe (lane^1: 0xB1, lane^2: 0x4E)
template<int CTRL>
__device__ __forceinline__ float dpp_add(float v) {
  int p = __builtin_amdgcn_update_dpp(0, __float_as_int(v), CTRL, 0xF, 0xF, true);
  return v + __int_as_float(p);
}

// packed fp32 FMA / ADD — CDNA full-rate dual fp32; inline asm also forces the
// weight operands into arch VGPRs (defeats AGPR parking + global rematerialization)
__device__ __forceinline__ v2f pk_fma(v2f a, v2f b, v2f c) {
  v2f d; asm("v_pk_fma_f32 %0, %1, %2, %3" : "=v"(d) : "v"(a), "v"(b), "v"(c)); return d;
}
__device__ __forceinline__ v2f pk_add(v2f a, v2f b) {
  v2f d; asm("v_pk_add_f32 %0, %1, %2" : "=v"(d) : "v"(a), "v"(b)); return d;
}

template<int N4>
__device__ __forceinline__ void loadrow_pk(v2f* w, const float* p) {
#pragma unroll
  for (int k = 0; k < N4; ++k) {
    float4 q = ((const float4*)p)[k];
    w[2*k]   = v2f{q.x, q.y};
    w[2*k+1] = v2f{q.z, q.w};
  }
}

template<int N>
__device__ __forceinline__ void pin(v2f* w) {
#pragma unroll
  for (int i = 0; i < N; ++i) asm volatile("" : "+v"(w[i]));
}

// dot(w[0:2*K4] pk-pairs, v[0:K4] float4) — 4 independent v2f accumulators
template<int K4>
__device__ __forceinline__ float dotp_pk(const v2f* w, const float4* v) {
  v2f a0{0.f,0.f}, a1{0.f,0.f}, a2{0.f,0.f}, a3{0.f,0.f};
#pragma unroll
  for (int k = 0; k < K4; ++k) {
    float4 t = v[k];
    v2f lo{t.x, t.y}, hi{t.z, t.w};
    if (k & 1) { a2 = pk_fma(w[2*k], lo, a2); a3 = pk_fma(w[2*k+1], hi, a3); }
    else       { a0 = pk_fma(w[2*k], lo, a0); a1 = pk_fma(w[2*k+1], hi, a1); }
  }
  v2f s = pk_add(pk_add(a0, a2), pk_add(a1, a3));
  return s.x + s.y;
}

// Lane map: q=tid&3 (k-quarter), g=(tid>>2)&3 (gate i,f,g,o), j=tid>>4 (unit).
// After the quad butterfly all 4 q-lanes hold gate g's full preactivation.
__device__ __forceinline__ float cell_update(float pre, float gsc, float gof, float& c) {
  float a  = fmaf(gsc, tanh_f(pre * gsc), gof);  // sigmoid for i,f,o ; tanh for g
  float i_s = swz<0x0010>(a);
  float f_s = swz<0x0090>(a);
  float g_t = swz<0x0110>(a);
  float o_s = swz<0x0190>(a);
  c = fmaf(f_s, c, i_s * g_t);
  return o_s * tanh_f(c);
}

// ---------------- prep: C0 = dWih0 @ fcW [256x64], fcbt = dWih0 @ fcb ----------------
__global__ void prep_kernel(const float* __restrict__ dWih0,
                            const float* __restrict__ fcW,
                            const float* __restrict__ fcb,
                            float* __restrict__ ws) {
  const int r = (int)blockIdx.x;           // 256
  const int jj = (int)threadIdx.x;         // 64
  const float* wr = dWih0 + (size_t)r * DIN;
  float acc = 0.f;
  for (int o = 0; o < DIN; ++o) acc = fmaf(wr[o], fcW[(size_t)o * HID + jj], acc);
  ws[(size_t)r * HID + jj] = acc;
  if (jj == 0) {
    float a = 0.f;
    for (int o = 0; o < DIN; ++o) a = fmaf(wr[o], fcb[o], a);
    ws[256 * HID + r] = a;
  }
}

// ---------------- persistent kernel: 1 block / batch element, 1024 threads ----------------
__global__ __launch_bounds__(1024, 4) void lstm_ae_kernel(
    const float* __restrict__ x,
    const float* __restrict__ eW0, const float* __restrict__ eU0,
    const float* __restrict__ ebi0, const float* __restrict__ ebh0,
    const float* __restrict__ eW1, const float* __restrict__ eU1,
    const float* __restrict__ ebi1, const float* __restrict__ ebh1,
    const float* __restrict__ dW0, const float* __restrict__ dU0,
    const float* __restrict__ dbi0, const float* __restrict__ dbh0,
    const float* __restrict__ dW1, const float* __restrict__ dU1,
    const float* __restrict__ dbi1, const float* __restrict__ dbh1,
    const float* __restrict__ fcW, const float* __restrict__ fcb,
    const float* __restrict__ ws,
    float* __restrict__ out)
{
  __shared__ __align__(16) float Abuf[BUFSZ];
  __shared__ __align__(16) float Bbuf[BUFSZ];

  const int tid = (int)threadIdx.x;
  const int b   = (int)blockIdx.x;
  const int q   = tid & 3;
  const int g   = (tid >> 2) & 3;
  const int j   = tid >> 4;
  const int r   = g * HID + j;
  const int jp  = j + 4 * (j >> 5);

  const float gsc = (g == 2) ? 1.0f : 0.5f;
  const float gof = (g == 2) ? 0.0f : 0.5f;

  // per-thread LDS offsets (all loop-invariant)
  const int o0  = 13 * q;              // enc op0 slice base (float4)
  const int o1  = 52 + 9 * q;          // enc op1 slice base (float4)
  const int xsl = tid + tid / 12;      // x stage float4 slot (tid<32)
  const int eh0slot = (tid & 15) ? (208 + jp) : ((j < 16) ? 136 + j : 140 + j);

  v2f w0[24];   // 48-float layer0 k-slice
  v2f w1[16];   // 32-float layer1 k-slice

  // ---------------- encoder weights (register-resident, pinned) ----------------
  if (q == 0)      loadrow_pk<12>(w0, eW0 + (size_t)r * DIN);
  else if (q == 1) loadrow_pk<12>(w0, eW0 + (size_t)r * DIN + 48);
  else if (q == 2) { loadrow_pk<8>(w0, eW0 + (size_t)r * DIN + 96);
                     loadrow_pk<4>(w0 + 16, eU0 + (size_t)r * HID); }
  else             loadrow_pk<12>(w0, eU0 + (size_t)r * HID + 16);
  if (q < 2) loadrow_pk<8>(w1, eW1 + (size_t)r * HID + 32 * q);
  else       loadrow_pk<8>(w1, eU1 + (size_t)r * HID + 32 * (q - 2));
  pin<24>(w0); pin<16>(w1);
  float bs0 = ebi0[r] + ebh0[r];
  float bs1 = ebi1[r] + ebh1[r];
  asm volatile("" : "+v"(bs0), "+v"(bs1));

  const float* xb = x + (size_t)b * (T_SEQ * DIN);
  const float4* xp = (const float4*)(xb + DIN) + (tid & 31);   // x_1 prefetch base

  if (tid >= 136 && tid < BUFSZ) { Abuf[tid] = 0.f; Bbuf[tid] = 0.f; }  // h slots = 0
  if (tid < 32) {
    float4 v = ((const float4*)xb)[tid];
    ((float4*)Abuf)[xsl] = v;                                  // x_0 (padded)
  }
  float c0 = 0.f, c1 = 0.f;
  __syncthreads();

  // ---------------- phase 1: staircase encoder, ONE barrier per tick ----------------
  // tick t: layer0(t) [reads R.op0] || layer1(t-1) [reads R.op1]; writes W only.
  auto tick = [&](float* R, float* W, bool do_l1, bool pf) {
    float4 xn;
    if (pf && tid < 32) xn = *xp;
    float p0 = dotp_pk<12>(w0, (const float4*)R + o0);
    float p1 = 0.f;
    if (do_l1) p1 = dotp_pk<8>(w1, (const float4*)R + o1);
    p0 = dpp_add<0xB1>(p0); p0 = dpp_add<0x4E>(p0); p0 += bs0;
    float h0v = cell_update(p0, gsc, gof, c0);
    if (do_l1) {
      p1 = dpp_add<0xB1>(p1); p1 = dpp_add<0x4E>(p1); p1 += bs1;
      float h1v = cell_update(p1, gsc, gof, c1);
      if ((tid & 15) == 0) W[280 + jp] = h1v;
    }
    if ((tid & 15) < 2) W[eh0slot] = h0v;
    if (pf) { if (tid < 32) ((float4*)W)[xsl] = xn; xp += 32; }
    __syncthreads();
  };

  tick(Abuf, Bbuf, false, true);                 // tick 0: layer0(0) only
#pragma unroll 1
  for (int t = 1; t < 1023; t += 2) {            // ticks 1..1022
    tick(Bbuf, Abuf, true, true);
    tick(Abuf, Bbuf, true, true);
  }
  tick(Bbuf, Abuf, true, false);                 // tick 1023 (no x prefetch)

  // tick 1024: layer1(1023) only — result stays in registers
  float h1f;
  {
    float p1 = dotp_pk<8>(w1, (const float4*)Abuf + o1);
    p1 = dpp_add<0xB1>(p1); p1 = dpp_add<0x4E>(p1); p1 += bs1;
    h1f = cell_update(p1, gsc, gof, c1);
  }

  // ---------------- transition: decoder weights + state re-layout into Abuf ----------------
  const float* C0 = ws;
  if (q < 2) loadrow_pk<8>(w0, C0  + (size_t)r * HID + 32 * q);
  else       loadrow_pk<8>(w0, dU0 + (size_t)r * HID + 32 * (q - 2));
  if (q < 2) loadrow_pk<8>(w1, dW1 + (size_t)r * HID + 32 * q);
  else       loadrow_pk<8>(w1, dU1 + (size_t)r * HID + 32 * (q - 2));
  pin<16>(w0); pin<16>(w1);
  bs0 = dbi0[r] + dbh0[r];
  bs1 = dbi1[r] + dbh1[r];
  float fcbt = ws[256 * HID + r];
  asm volatile("" : "+v"(bs0), "+v"(bs1), "+v"(fcbt));

  const int e  = tid & 7;      // fc k-slice (8 floats)
  const int oo = tid >> 3;     // fc output index [0,128)
  const int fce = 2 * e + (e >> 2);
  v2f fw[4];
  loadrow_pk<2>(fw, fcW + (size_t)oo * HID + 8 * e);
  pin<4>(fw);
  float fb = fcb[oo];

  c0 = tanh_f(c0);
  c1 = tanh_f(c1);
  float hv0 = 0.f;
  if (tid < 64) hv0 = tanh_f(Abuf[(tid < 16) ? 136 + tid : 140 + tid]);  // h0(1023)
  float hv1 = tanh_f(h1f);
  __syncthreads();                               // all reads of Abuf done
  if (tid < 64) {
    int pp = tid + 4 * (tid >> 5);
    Abuf[72 + pp] = hv0;                         // dec op0 h0 slot
    Abuf[144 + pp] = hv0;                        // dec op1 h0 slot
  }
  if ((tid & 15) == 0) Abuf[216 + jp] = hv1;     // dec op1 h1 slot (state init)
  if (tid < 68) Abuf[tid] = 0.f;                 // dec op0 h1 slot = 0 (t=0: no feedback)
  __syncthreads();

  float* outb = out + (size_t)b * (T_SEQ * DOUT);
  const int do0 = 9 * q;
  const int do1 = 36 + 9 * q;
  const int ds0 = (tid & 15) ? (144 + jp) : (72 + jp);
  const int ds1 = (tid & 15) ? (216 + jp) : jp;

  // ---------------- phase 2: autoregressive decoder (fc folded via C0) ----------------
  auto dec_step = [&](float* R_, float* W_, int t) {
    float p0 = dotp_pk<8>(w0, (const float4*)R_ + do0);     // [h1(t-1) | h0(t-1)]
    float s  = dotp_pk<2>(fw, (const float4*)R_ + fce);     // fc on h1(t-1)
    p0 = dpp_add<0xB1>(p0); p0 = dpp_add<0x4E>(p0);
    p0 += bs0 + ((t > 0) ? fcbt : 0.f);
    float h0v = cell_update(p0, gsc, gof, c0);
    if ((tid & 15) < 2) W_[ds0] = h0v;
    s = dpp_add<0xB1>(s); s = dpp_add<0x4E>(s); s += swz<0x101F>(s);
    if (e == 0 && t > 0) outb[(size_t)(t - 1) * DOUT + oo] = s + fb;
    __syncthreads();

    const float* bb = (q < 2) ? W_ : R_;                    // [h0new | h1old]
    float p1 = dotp_pk<8>(w1, (const float4*)bb + do1);
    p1 = dpp_add<0xB1>(p1); p1 = dpp_add<0x4E>(p1); p1 += bs1;
    float h1v = cell_update(p1, gsc, gof, c1);
    if ((tid & 15) < 2) W_[ds1] = h1v;
    __syncthreads();
  };

#pragma unroll 1
  for (int t = 0; t < T_SEQ; t += 2) {
    dec_step(Abuf, Bbuf, t);
    dec_step(Bbuf, Abuf, t + 1);
  }

  // epilogue: pred(1023) from final h1 (in Abuf op0-h1)
  float s = dotp_pk<2>(fw, (const float4*)Abuf + fce);
  s = dpp_add<0xB1>(s); s = dpp_add<0x4E>(s); s += swz<0x101F>(s);
  if (e == 0) outb[(size_t)(T_SEQ - 1) * DOUT + oo] = s + fb;
}

extern "C" void kernel_launch(void* const* d_in, const int* in_sizes, int n_in,
                              void* d_out, int out_size, void* d_ws, size_t ws_size,
                              hipStream_t stream) {
  (void)in_sizes; (void)n_in; (void)ws_size; (void)out_size;
  const float* x    = (const float*)d_in[0];
  const float* eW0  = (const float*)d_in[1];
  const float* eU0  = (const float*)d_in[2];
  const float* ebi0 = (const float*)d_in[3];
  const float* ebh0 = (const float*)d_in[4];
  const float* eW1  = (const float*)d_in[5];
  const float* eU1  = (const float*)d_in[6];
  const float* ebi1 = (const float*)d_in[7];
  const float* ebh1 = (const float*)d_in[8];
  const float* dW0  = (const float*)d_in[9];
  const float* dU0  = (const float*)d_in[10];
  const float* dbi0 = (const float*)d_in[11];
  const float* dbh0 = (const float*)d_in[12];
  const float* dW1  = (const float*)d_in[13];
  const float* dU1  = (const float*)d_in[14];
  const float* dbi1 = (const float*)d_in[15];
  const float* dbh1 = (const float*)d_in[16];
  const float* fcW  = (const float*)d_in[17];
  const float* fcb  = (const float*)d_in[18];
  float* ws  = (float*)d_ws;
  float* out = (float*)d_out;

  hipLaunchKernelGGL(prep_kernel, dim3(256), dim3(64), 0, stream, dW0, fcW, fcb, ws);
  hipLaunchKernelGGL(lstm_ae_kernel, dim3(NBATCH), dim3(1024), 0, stream,
                     x, eW0, eU0, ebi0, ebh0, eW1, eU1, ebi1, ebh1,
                     dW0, dU0, dbi0, dbh0, dW1, dU1, dbi1, dbh1,
                     fcW, fcb, ws, out);
}